// Round 14
// baseline (584.173 us; speedup 1.0000x reference)
//
#include <hip/hip_runtime.h>
#include <math.h>

typedef unsigned int u32;
typedef unsigned short u16;
typedef unsigned long long u64;
typedef _Float16 h8v __attribute__((ext_vector_type(8)));
typedef float f4v __attribute__((ext_vector_type(4)));
typedef u32 u4v __attribute__((ext_vector_type(4)));

#define B_ 4
#define C_ 64
#define HW 4096
#define L_ 4096
#define D_ 576
#define MW 256
#define SCALE 10.0f
#define EPS 1e-4f
#define TAU 0.015f
#define PAIRCAP 262144

__device__ __forceinline__ u16 f16b(float x) {
  union { _Float16 h; u16 u; } c; c.h = (_Float16)x; return c.u;
}
__device__ __forceinline__ float f16f(u16 v) {
  union { u16 u; _Float16 h; } c; c.u = v; return (float)c.h;
}

__device__ __forceinline__ void gld16(const void* g, void* l) {
  __builtin_amdgcn_global_load_lds((const __attribute__((address_space(1))) void*)g,
                                   (__attribute__((address_space(3))) void*)l, 16, 0, 0);
}

// ---------- upfront kernels ----------
__global__ __launch_bounds__(256) void k_mp(const float* __restrict__ mask, float* __restrict__ mp) {
  int idx = blockIdx.x * 256 + threadIdx.x;
  int b = idx >> 12, p = idx & 4095;
  int y = p >> 6, x = p & 63;
  const float* mb = mask + (size_t)b * MW * MW;
  float s = 0.f;
  #pragma unroll
  for (int i = 0; i < 4; ++i)
    #pragma unroll
    for (int j = 0; j < 4; ++j)
      s += mb[(y * 4 + i) * MW + x * 4 + j];
  mp[idx] = s * (1.f / 16.f);
}

__global__ __launch_bounds__(256) void k_pre2(const float* __restrict__ f, const float* __restrict__ mp,
                                              float* __restrict__ m0, float* __restrict__ fm) {
  int blk = blockIdx.x;
  if (blk < 144) {
    int idx = blk * 256 + threadIdx.x;   // l*9 + t
    int l = idx / 9, t = idx - l * 9;
    int ly = l >> 6, lx = l & 63;
    int i = t / 3, j = t - i * 3;
    int yy = ly + i - 1, xx = lx + j - 1;
    float v = 0.f;
    if ((unsigned)yy < 64u && (unsigned)xx < 64u) v = mp[(yy << 6) + xx];
    m0[idx] = v;
  } else {
    int idx = (blk - 144) * 256 + threadIdx.x;
    int p = idx & 4095;
    int b = idx >> 18;
    fm[idx] = f[idx] * (1.f - mp[(b << 12) + p]);
  }
}

// ---------- per-batch prep: LDS-staged patch generation ----------
// Block ly<64: stage img+fm rows ly-1..ly+1 (all c) in LDS; emit w_h[l][d],
// wT_h[d][l], fp_h[l][d] (all fp16, coalesced) + norme/normv. Blocks 64..79: zero.
__device__ __forceinline__ float ldsval(const float* __restrict__ s, int lloc, int c, int t) {
  int i2 = t / 3, j2 = t - i2 * 3;
  int xx = lloc + j2 - 1;
  float v = 0.f;
  if ((unsigned)xx < 64u) v = s[(((i2 << 6) + c) << 6) + xx];
  return v;
}

__global__ __launch_bounds__(512) void k_prepw(const float* __restrict__ bimg, const float* __restrict__ fmb,
                                               const float* __restrict__ m0,
                                               u16* __restrict__ w_h, u16* __restrict__ fp_h,
                                               u16* __restrict__ wT_h,
                                               double* __restrict__ norme, float* __restrict__ normv,
                                               int* __restrict__ rcount, int* __restrict__ pcount,
                                               u64* __restrict__ rbest) {
  if (blockIdx.x >= 64) {                // zero section
    int e = (blockIdx.x - 64) * 512 + threadIdx.x;
    if (e < 4096) rbest[e] = 0ull;
    if (e == 0) { *rcount = 0; *pcount = 0; }
    return;
  }
  __shared__ float s_img[12288];         // [dy][c][64]
  __shared__ float s_fm[12288];
  __shared__ float m0s[576];
  const int ly = blockIdx.x;
  const int tid = threadIdx.x;

  #pragma unroll
  for (int i = 0; i < 6; ++i) {
    int slot = tid + i * 512;            // 0..3071 float4 slots
    int dy = slot >> 10, rem = slot & 1023;
    int c = rem >> 4, xq = rem & 15;
    int yy = ly + dy - 1;
    f4v vi = {0.f, 0.f, 0.f, 0.f}, vf = {0.f, 0.f, 0.f, 0.f};
    if ((unsigned)yy < 64u) {
      vi = *(const f4v*)&bimg[(c << 12) + (yy << 6) + (xq << 2)];
      vf = *(const f4v*)&fmb[(c << 12) + (yy << 6) + (xq << 2)];
    }
    *(f4v*)&s_img[slot << 2] = vi;
    *(f4v*)&s_fm[slot << 2] = vf;
  }
  for (int t2 = tid; t2 < 576; t2 += 512) m0s[t2] = m0[ly * 576 + t2];
  __syncthreads();

  // w_h [l][576] fp16 pairs (coalesced)
  u32* wh32 = (u32*)w_h;
  u32* fp32p = (u32*)fp_h;
  #pragma unroll
  for (int i = 0; i < 36; ++i) {
    int g2 = tid + i * 512;              // 0..18431
    int idx = g2 * 2;
    int ll = idx / 576, d0 = idx - ll * 576;
    int c0 = d0 / 9, t0 = d0 - c0 * 9;
    int d1 = d0 + 1;
    int c1 = d1 / 9, t1 = d1 - c1 * 9;
    float w0 = ldsval(s_img, ll, c0, t0) * m0s[ll * 9 + t0];
    float w1 = ldsval(s_img, ll, c1, t1) * m0s[ll * 9 + t1];
    wh32[ly * 18432 + g2] = (u32)f16b(w0) | ((u32)f16b(w1) << 16);
    float p0 = ldsval(s_fm, ll, c0, t0);
    float p1 = ldsval(s_fm, ll, c1, t1);
    fp32p[ly * 18432 + g2] = (u32)f16b(p0) | ((u32)f16b(p1) << 16);
  }

  // wT_h [d][4096] fp16 pairs along l (same values as w_h, transposed)
  u32* wT32 = (u32*)wT_h;
  #pragma unroll
  for (int i = 0; i < 36; ++i) {
    int g2 = tid + i * 512;              // 0..18431
    int d = g2 >> 5, lxp = g2 & 31;
    int c = d / 9, t = d - c * 9;
    float w0 = ldsval(s_img, 2 * lxp, c, t) * m0s[(2 * lxp) * 9 + t];
    float w1 = ldsval(s_img, 2 * lxp + 1, c, t) * m0s[(2 * lxp + 1) * 9 + t];
    wT32[d * 2048 + ly * 32 + lxp] = (u32)f16b(w0) | ((u32)f16b(w1) << 16);
  }

  // norms: 8 waves x 8 l's each, lane covers d = lane + k*64 (k<9)
  int wid = tid >> 6, lane = tid & 63;
  #pragma unroll
  for (int it = 0; it < 8; ++it) {
    int lloc = wid * 8 + it;
    double ss = 0.0;
    #pragma unroll
    for (int k = 0; k < 9; ++k) {
      int d = lane + k * 64;
      int c = d / 9, t = d - c * 9;
      float wv = ldsval(s_img, lloc, c, t) * m0s[lloc * 9 + t];
      ss += (double)wv * (double)wv;
    }
    #pragma unroll
    for (int off = 32; off; off >>= 1) ss += __shfl_down(ss, off);
    if (lane == 0) {
      double n = sqrt(ss + (double)EPS);
      norme[ly * 64 + lloc] = n;
      normv[ly * 64 + lloc] = (float)n;
    }
  }
}

// ---------- GEMM1 + fused softmax partials; 3-buffer counted-vmcnt pipeline ----------
#define STAGE1(buf, k0) do {                                                             \
    int bb = (buf) * 24576;                                                              \
    _Pragma("unroll") for (int i_ = 0; i_ < 4; ++i_) {                                   \
      int s_ = tid + i_ * 256; int r_ = s_ >> 2, ks_ = s_ & 3;                           \
      int kg_ = ks_ ^ ((r_ >> 1) & 3);                                                   \
      gld16(A + (u32)(m0 + r_) * 576u + (u32)((k0) + kg_ * 8),                           \
            (char*)lds + bb + s_ * 16); }                                                \
    _Pragma("unroll") for (int i_ = 0; i_ < 2; ++i_) {                                   \
      int s_ = tid + i_ * 256; int r_ = s_ >> 2, ks_ = s_ & 3;                           \
      int kg_ = ks_ ^ ((r_ >> 1) & 3);                                                   \
      gld16(Bm + (u32)(n0 + r_) * 576u + (u32)((k0) + kg_ * 8),                          \
            (char*)lds + bb + 16384 + s_ * 16); }                                        \
  } while (0)

__global__ __launch_bounds__(256, 2) void k_mfma1(
    const u16* __restrict__ A, const u16* __restrict__ Bm, const float* __restrict__ normv,
    u16* __restrict__ P, float* __restrict__ bm1, int* __restrict__ bi1,
    float* __restrict__ bsum, int* __restrict__ bflg)
{
  __shared__ u32 lds[18432];             // 72KB = 3 x (A 16KB + B 8KB)
  u16* ldsu = (u16*)lds;
  const int tid = threadIdx.x;
  const int lane = tid & 63, wid = tid >> 6;
  const int wrM = wid >> 1, wc = wid & 1;
  const int kq = lane >> 4, li = lane & 15;

  int nwg = gridDim.x * gridDim.y;       // 512
  int bid = blockIdx.y * gridDim.x + blockIdx.x;
  int cpx = nwg >> 3;
  int swz = (bid & 7) * cpx + (bid >> 3);
  int bx = swz % gridDim.x, by = swz / gridDim.x;
  const int m0 = by * 256, n0 = bx * 128;

  f4v acc[8][4] = {};

  STAGE1(0, 0);
  STAGE1(1, 32);

  for (int kc = 0; kc < 18; ++kc) {
    if (kc + 1 < 18) { asm volatile("s_waitcnt vmcnt(6)" ::: "memory"); }
    else             { asm volatile("s_waitcnt vmcnt(0)" ::: "memory"); }
    __builtin_amdgcn_s_barrier();
    __builtin_amdgcn_sched_barrier(0);
    if (kc + 2 < 18) STAGE1((kc + 2) % 3, (kc + 2) * 32);

    int cb = (kc % 3) * 12288;
    h8v ah[8];
    #pragma unroll
    for (int mf = 0; mf < 8; ++mf) {
      int r = wrM * 128 + mf * 16 + li;
      int off = r * 32 + (kq ^ ((r >> 1) & 3)) * 8;
      ah[mf] = *(const h8v*)&ldsu[cb + off];
    }
    #pragma unroll
    for (int nf = 0; nf < 4; ++nf) {
      int r = wc * 64 + nf * 16 + li;
      int off = r * 32 + (kq ^ ((r >> 1) & 3)) * 8;
      h8v bh = *(const h8v*)&ldsu[cb + 8192 + off];
      #pragma unroll
      for (int mf = 0; mf < 8; ++mf)
        acc[mf][nf] = __builtin_amdgcn_mfma_f32_16x16x32_f16(ah[mf], bh, acc[mf][nf], 0, 0, 0);
    }
  }
  __syncthreads();                       // loop done; reuse LDS for stats

  float* ldsf = (float*)lds;
  int*   ldsi = (int*)lds;

  float invn4[4];
  #pragma unroll
  for (int nf = 0; nf < 4; ++nf) invn4[nf] = 1.0f / normv[n0 + wc * 64 + nf * 16 + li];
  #pragma unroll
  for (int mf = 0; mf < 8; ++mf)
    #pragma unroll
    for (int nf = 0; nf < 4; ++nf)
      #pragma unroll
      for (int rr = 0; rr < 4; ++rr)
        acc[mf][nf][rr] *= invn4[nf];

  // pass A: per-(row, wc*16+li) max over 4 nf cols
  #pragma unroll
  for (int mf = 0; mf < 8; ++mf)
    #pragma unroll
    for (int rr = 0; rr < 4; ++rr) {
      int row = wrM * 128 + mf * 16 + kq * 4 + rr;
      float tv = fmaxf(fmaxf(acc[mf][0][rr], acc[mf][1][rr]), fmaxf(acc[mf][2][rr], acc[mf][3][rr]));
      ldsf[row * 33 + wc * 16 + li] = tv;
    }
  __syncthreads();
  float rV1 = -3.4e38f;
  #pragma unroll
  for (int k = 0; k < 32; ++k) rV1 = fmaxf(rV1, ldsf[tid * 33 + k]);
  ldsf[8448 + tid] = rV1;
  ldsi[8704 + tid] = 0x7fffffff;
  ldsi[8960 + tid] = 0;
  __syncthreads();

  // pass C: exp + P store + sum partial + equality-argmax + near-count
  #pragma unroll
  for (int mf = 0; mf < 8; ++mf)
    #pragma unroll
    for (int rr = 0; rr < 4; ++rr) {
      int row = wrM * 128 + mf * 16 + kq * 4 + rr;
      float v1 = ldsf[8448 + row];
      int m = m0 + row;
      float sum4 = 0.f;
      int locmin = 0x7fffffff, loccnt = 0;
      #pragma unroll
      for (int nf = 0; nf < 4; ++nf) {
        float sv = acc[mf][nf][rr];
        int n = n0 + wc * 64 + nf * 16 + li;
        float p = __expf((sv - v1) * SCALE);
        P[(u32)m * 4096u + (u32)n] = f16b(p);
        sum4 += p;
        if (sv == v1 && n < locmin) locmin = n;
        if (sv >= v1 - TAU) loccnt++;
      }
      ldsf[row * 33 + wc * 16 + li] = sum4;
      if (locmin != 0x7fffffff) atomicMin(&ldsi[8704 + row], locmin);
      if (loccnt) atomicAdd(&ldsi[8960 + row], loccnt);
    }
  __syncthreads();

  {
    float rS = 0.f;
    #pragma unroll
    for (int k = 0; k < 32; ++k) rS += ldsf[tid * 33 + k];
    int q = m0 + tid, j = n0 >> 7;
    bm1[q * 32 + j] = ldsf[8448 + tid];
    bi1[q * 32 + j] = ldsi[8704 + tid];
    bsum[q * 32 + j] = rS;
    bflg[q * 32 + j] = (ldsi[8960 + tid] >= 2) ? 1 : 0;
  }
}

// ---------- softmax reduce across 32 l-blocks ----------
__global__ __launch_bounds__(256) void k_smred(const float* __restrict__ bm1, const int* __restrict__ bi1,
                                               const float* __restrict__ bsum, const int* __restrict__ bflg,
                                               float* __restrict__ fac, float* __restrict__ gm,
                                               float* __restrict__ offs, int* __restrict__ rflag,
                                               int* __restrict__ rlist, int* __restrict__ rcount) {
  int q = blockIdx.x * 4 + (threadIdx.x >> 6);
  int lane = threadIdx.x & 63;
  if (lane >= 32) return;
  float mj = bm1[q * 32 + lane];
  int   fj = bflg[q * 32 + lane];
  float v1 = mj; int i1 = bi1[q * 32 + lane];
  #pragma unroll
  for (int d = 1; d < 32; d <<= 1) {
    float ov1 = __shfl_xor(v1, d); int oi1 = __shfl_xor(i1, d);
    if (ov1 > v1 || (ov1 == v1 && oi1 < i1)) { v1 = ov1; i1 = oi1; }
  }
  // v1 = gmax, i1 = global argmax
  float e = __expf((mj - v1) * SCALE);
  float Z = bsum[q * 32 + lane] * e;
  #pragma unroll
  for (int d = 1; d < 32; d <<= 1) Z += __shfl_xor(Z, d);
  fac[q * 32 + lane] = e / Z;
  int jwin = i1 >> 7;
  int near = (lane != jwin) && (mj >= v1 - TAU);
  u64 bal = __ballot(near);
  int wflg = __shfl(fj, jwin);
  if (lane == 0) {
    gm[q] = v1;
    offs[q] = (float)i1;
    int fl = (bal != 0ull || wflg) ? 1 : 0;
    rflag[q] = fl;
    if (fl) {
      int pos = atomicAdd(rcount, 1);
      if (pos < 4096) rlist[pos] = q;
    }
  }
}

// ---------- attn scale (in-place on P) + candidate emission for flagged rows ----------
__global__ __launch_bounds__(256) void k_attnc(u16* __restrict__ P, const float* __restrict__ fac,
                                               const int* __restrict__ rflag, const float* __restrict__ bm1,
                                               const float* __restrict__ gm,
                                               u32* __restrict__ pairs, int* __restrict__ pcount) {
  int gid = blockIdx.x * 256 + threadIdx.x;  // 2M threads; block covers half a q-row
  u4v v = ((u4v*)P)[gid];
  int q = gid >> 9;
  int l0 = (gid & 511) * 8;
  int j = l0 >> 7;

  if (rflag[q]) {
    float thr = gm[q] - 2.0f * TAU - 1e-3f;
    float bmj = bm1[q * 32 + j];
    if (bmj >= thr) {
      u16 bits = f16b(__expf((thr - bmj) * SCALE));   // in [0.73, 1]
      u16 pt = bits > 4 ? (u16)(bits - 4) : (u16)1;   // ULP slack
      #pragma unroll
      for (int k = 0; k < 4; ++k) {
        u16 lo = (u16)v[k], hi = (u16)(v[k] >> 16);
        if (lo >= pt) {
          int pos = atomicAdd(pcount, 1);
          if (pos < PAIRCAP) pairs[pos] = ((u32)q << 12) | (u32)(l0 + 2 * k);
        }
        if (hi >= pt) {
          int pos = atomicAdd(pcount, 1);
          if (pos < PAIRCAP) pairs[pos] = ((u32)q << 12) | (u32)(l0 + 2 * k + 1);
        }
      }
    }
  }

  _Float16 fh = (_Float16)fac[q * 32 + j];
  union { u4v u; h8v h; } c; c.u = v;
  c.h *= (h8v){fh, fh, fh, fh, fh, fh, fh, fh};
  ((u4v*)P)[gid] = c.u;
}

// ---------- GEMM2: G[z][n][q] (transposed out), 3-buffer counted-vmcnt, split-K=4 ----------
#define STG2(buf, k0) do {                                                               \
    int bb = (buf) * 24576;                                                              \
    _Pragma("unroll") for (int i_ = 0; i_ < 4; ++i_) {                                   \
      int s_ = tid + i_ * 256; int r_ = s_ >> 2, ks_ = s_ & 3;                           \
      int kg_ = ks_ ^ ((r_ >> 1) & 3);                                                   \
      gld16(A + (u32)(m0 + r_) * 4096u + (u32)((k0) + kg_ * 8),                          \
            (char*)lds + bb + s_ * 16); }                                                \
    _Pragma("unroll") for (int i_ = 0; i_ < 2; ++i_) {                                   \
      int s_ = tid + i_ * 256; int r_ = s_ >> 2, ks_ = s_ & 3;                           \
      int kg_ = ks_ ^ ((r_ >> 1) & 3);                                                   \
      gld16(Bm + (u32)(n0 + r_) * 4096u + (u32)((k0) + kg_ * 8),                         \
            (char*)lds + bb + 16384 + s_ * 16); }                                        \
  } while (0)

__global__ __launch_bounds__(256, 2) void k_gemm2(
    const u16* __restrict__ A, const u16* __restrict__ Bm, float* __restrict__ Gpart)
{
  __shared__ u32 lds[18432];             // 72KB = 3 buffers
  u16* ldsu = (u16*)lds;
  const int tid = threadIdx.x;
  const int lane = tid & 63, wid = tid >> 6;
  const int wrM = wid >> 1, wc = wid & 1;
  const int kq = lane >> 4, li = lane & 15;

  int nwg = gridDim.x * gridDim.y;       // 80
  int bid = blockIdx.y * gridDim.x + blockIdx.x;
  int cpx = nwg >> 3;
  int swz = (bid & 7) * cpx + (bid >> 3);
  int bx = swz % gridDim.x, by = swz / gridDim.x;
  const int m0 = by * 256, n0 = bx * 128;
  const int kz = blockIdx.z * 1024;

  f4v acc[8][4] = {};

  STG2(0, kz);
  STG2(1, kz + 32);

  for (int kc = 0; kc < 32; ++kc) {
    if (kc + 1 < 32) { asm volatile("s_waitcnt vmcnt(6)" ::: "memory"); }
    else             { asm volatile("s_waitcnt vmcnt(0)" ::: "memory"); }
    __builtin_amdgcn_s_barrier();
    __builtin_amdgcn_sched_barrier(0);
    if (kc + 2 < 32) STG2((kc + 2) % 3, kz + (kc + 2) * 32);

    int cb = (kc % 3) * 12288;
    h8v ah[8];
    #pragma unroll
    for (int mf = 0; mf < 8; ++mf) {
      int r = wrM * 128 + mf * 16 + li;
      int off = r * 32 + (kq ^ ((r >> 1) & 3)) * 8;
      ah[mf] = *(const h8v*)&ldsu[cb + off];
    }
    #pragma unroll
    for (int nf = 0; nf < 4; ++nf) {
      int r = wc * 64 + nf * 16 + li;
      int off = r * 32 + (kq ^ ((r >> 1) & 3)) * 8;
      h8v bh = *(const h8v*)&ldsu[cb + 8192 + off];
      #pragma unroll
      for (int mf = 0; mf < 8; ++mf)
        acc[mf][nf] = __builtin_amdgcn_mfma_f32_16x16x32_f16(ah[mf], bh, acc[mf][nf], 0, 0, 0);
    }
  }

  // transposed store: G[n][q], lane writes one aligned float4 (4 consecutive q)
  float* Cf = Gpart + (size_t)blockIdx.z * 2359296;
  #pragma unroll
  for (int nf = 0; nf < 4; ++nf) {
    int n = n0 + wc * 64 + nf * 16 + li;
    if (n < D_) {
      #pragma unroll
      for (int mf = 0; mf < 8; ++mf) {
        int m = m0 + wrM * 128 + mf * 16 + kq * 4;
        *(f4v*)&Cf[(u32)n * 4096u + (u32)m] = acc[mf][nf];
      }
    }
  }
}

// ---------- f64 rescue: one wave per (q,l) pair ----------
__global__ __launch_bounds__(256) void k_rpairs(const u32* __restrict__ pairs, const int* __restrict__ pcount,
                                                const float* __restrict__ b0, const float* __restrict__ m0,
                                                const float* __restrict__ fmb, const double* __restrict__ norme,
                                                u64* __restrict__ rbest) {
  int nw = gridDim.x * 4;
  int gw = blockIdx.x * 4 + (threadIdx.x >> 6);
  int lane = threadIdx.x & 63;
  int cnt = *pcount; if (cnt > PAIRCAP) cnt = PAIRCAP;
  for (int e = gw; e < cnt; e += nw) {
    u32 pr = pairs[e];
    int q = pr >> 12, l = pr & 4095;
    int qy = q >> 6, qx = q & 63, ly = l >> 6, lx = l & 63;
    int c = lane;
    double dot = 0.0;
    #pragma unroll
    for (int t = 0; t < 9; ++t) {
      int i = t / 3, j = t - (t / 3) * 3;
      int wy = ly + i - 1, wx = lx + j - 1;
      int fy = qy + i - 1, fx = qx + j - 1;
      float wv = 0.f, fv = 0.f;
      if ((unsigned)wy < 64u && (unsigned)wx < 64u) wv = b0[(c << 12) + (wy << 6) + wx] * m0[l * 9 + t];
      if ((unsigned)fy < 64u && (unsigned)fx < 64u) fv = fmb[(c << 12) + (fy << 6) + fx];
      dot += (double)wv * (double)fv;
    }
    #pragma unroll
    for (int off = 32; off; off >>= 1) dot += __shfl_down(dot, off);
    if (lane == 0) {
      double sc = dot / norme[l];
      u64 bbits = (u64)__double_as_longlong(sc);
      if (bbits >> 63) bbits = ~bbits; else bbits |= 0x8000000000000000ull;
      u64 key = (bbits & ~0xFFFull) | (u64)(4095 - l);
      atomicMax(rbest + q, key);
    }
  }
}

// ---------- fold (coalesced reads from G[z][n][q]) + rescue finalize ----------
__global__ __launch_bounds__(256) void k_foldfin(const float* __restrict__ Gp, float* __restrict__ yout,
                                                 const int* __restrict__ rlist, const int* __restrict__ rcount,
                                                 const u64* __restrict__ rbest, float* __restrict__ offs) {
  if (blockIdx.x < 1024) {
    int idx = blockIdx.x * 256 + threadIdx.x;   // c*4096 + p
    int c = idx >> 12, p = idx & 4095;
    int yy = p >> 6, xx = p & 63;
    float s = 0.f;
    #pragma unroll
    for (int t = 0; t < 9; ++t) {
      int i = t / 3, j = t - (t / 3) * 3;
      int qy = yy + 1 - i, qx = xx + 1 - j;
      if ((unsigned)qy < 64u && (unsigned)qx < 64u) {
        u32 base = (u32)(c * 9 + t) * 4096u + (u32)((qy << 6) + qx);
        #pragma unroll
        for (int z = 0; z < 4; ++z) s += Gp[(size_t)z * 2359296 + base];
      }
    }
    yout[idx] = s;
  } else {
    int cnt = *rcount; if (cnt > 4096) cnt = 4096;
    int e = (blockIdx.x - 1024) * 256 + threadIdx.x;
    if (e < cnt) {
      int q = rlist[e];
      offs[q] = (float)(4095 - (int)(rbest[q] & 0xFFFull));
    }
  }
}

extern "C" void kernel_launch(void* const* d_in, const int* in_sizes, int n_in,
                              void* d_out, int out_size, void* d_ws, size_t ws_size,
                              hipStream_t stream) {
  const float* b_in = (const float*)d_in[0];
  const float* f_in = (const float*)d_in[1];
  const float* mask = (const float*)d_in[2];
  float* out = (float*)d_out;

  char* ws = (char*)d_ws;
  float*  mp     = (float*)(ws + 0);          // 64KB
  float*  m0buf  = (float*)(ws + 65536);      // 144KB
  float*  fm     = (float*)(ws + 212992);     // 4MB
  float*  normv  = (float*)(ws + 4407296);    // 16KB
  double* norme  = (double*)(ws + 4423680);   // 32KB
  u16*    w_h    = (u16*)(ws + 4456448);      // 4.7MB
  u16*    fp_h   = (u16*)(ws + 9175040);      // 4.7MB
  u16*    wT_h   = (u16*)(ws + 13893632);     // 5.24MB
  u16*    P      = (u16*)(ws + 19136512);     // 32MB
  int*    rflag  = (int*)(ws + 52690944);     // 16KB
  float*  bm1    = (float*)(ws + 86245376);   // 512KB
  int*    bi1    = (int*)(ws + 86769664);     // 512KB
  float*  bsum   = (float*)(ws + 87293952);   // 512KB
  int*    bflg   = (int*)(ws + 87818240);     // 512KB
  float*  fac    = (float*)(ws + 88342528);   // 512KB
  float*  gm     = (float*)(ws + 88866816);   // 16KB
  float*  Gpart  = (float*)(ws + 88883200);   // 37.7MB
  int*    rcount = (int*)(ws + 126631936);
  int*    pcount = (int*)(ws + 126631940);
  int*    rlist  = (int*)(ws + 126632192);    // 16KB
  u64*    rbest  = (u64*)(ws + 126648576);    // 32KB
  u32*    pairs  = (u32*)(ws + 126681344);    // 1MB -> ends 127729920

  k_mp<<<64, 256, 0, stream>>>(mask, mp);
  k_pre2<<<4240, 256, 0, stream>>>(f_in, mp, m0buf, fm);

  for (int b = 0; b < B_; ++b) {
    const float* bimg = b_in + (size_t)b * C_ * HW;
    const float* fmb  = fm + (size_t)b * C_ * HW;
    float* offs_b = out + (size_t)B_ * C_ * HW + (size_t)b * HW;

    k_prepw<<<80, 512, 0, stream>>>(bimg, fmb, m0buf, w_h, fp_h, wT_h,
                                    norme, normv, rcount, pcount, rbest);
    k_mfma1<<<dim3(32, 16), 256, 0, stream>>>(fp_h, w_h, normv, P, bm1, bi1, bsum, bflg);
    k_smred<<<1024, 256, 0, stream>>>(bm1, bi1, bsum, bflg, fac, gm, offs_b, rflag, rlist, rcount);
    k_attnc<<<8192, 256, 0, stream>>>(P, fac, rflag, bm1, gm, pairs, pcount);
    k_gemm2<<<dim3(5, 16, 4), 256, 0, stream>>>(P, wT_h, Gpart);
    k_rpairs<<<512, 256, 0, stream>>>(pairs, pcount, bimg, m0buf, fmb, norme, rbest);
    k_foldfin<<<1040, 256, 0, stream>>>(Gpart, out + (size_t)b * C_ * HW,
                                        rlist, rcount, rbest, offs_b);
  }
}